// Round 8
// baseline (761.952 us; speedup 1.0000x reference)
//
#include <hip/hip_runtime.h>
#include <cmath>

#define NPTS 10000
#define NBATCH 8
#define NFEAT 16
#define DDIM 128
#define NBINS 20
#define BINSZ 500
#define KSEL 5
#define EDGES_PER_BATCH (NPTS*KSEL)        // 50000
#define EDGE_TOT (NBATCH*EDGES_PER_BATCH)  // 400000
#define TOTPTS (NBATCH*NPTS)               // 80000
#define NGRP (NBATCH*NBINS)                // 160
#define PROWS 512                          // padded rows per (grp,ch) partial slab

// enc = ELU(X@W1+b1)@W2+b2 ; 32 points per block, 256 threads.
// Block 0 also zeroes the bin histogram (k_bins runs after k_enc completes).
__global__ __launch_bounds__(256) void k_enc(const float* __restrict__ X,
        const float* __restrict__ W1, const float* __restrict__ b1,
        const float* __restrict__ W2, const float* __restrict__ b2,
        float* __restrict__ enc, int* __restrict__ hist) {
    __shared__ float hT[128*36];
    const int tid = threadIdx.x;
    const int P0 = blockIdx.x * 32;
    if (blockIdx.x == 0 && tid < NBATCH*NBINS) hist[tid] = 0;
    #pragma unroll
    for (int i = 0; i < 16; ++i) {
        int idx = i*256 + tid;
        int p = idx >> 7;
        int j = idx & 127;
        const float* xr = X + (size_t)(P0 + p)*NFEAT;
        float h = b1[j];
        #pragma unroll
        for (int f = 0; f < 16; ++f) h += xr[f] * W1[f*128 + j];
        h = (h > 0.f) ? h : expm1f(h);
        hT[j*36 + p] = h;
    }
    __syncthreads();
    const int jt = tid & 31, pt = tid >> 5;
    const int j0 = jt*4, p0 = pt*4;
    float acc[4][4];
    #pragma unroll
    for (int ep = 0; ep < 4; ++ep)
        #pragma unroll
        for (int ej = 0; ej < 4; ++ej) acc[ep][ej] = b2[j0+ej];
    for (int k = 0; k < 128; ++k) {
        float4 hv = *(const float4*)&hT[k*36 + p0];
        float4 wv = *(const float4*)&W2[k*128 + j0];
        float hvv[4] = {hv.x,hv.y,hv.z,hv.w};
        float wvv[4] = {wv.x,wv.y,wv.z,wv.w};
        #pragma unroll
        for (int ep = 0; ep < 4; ++ep)
            #pragma unroll
            for (int ej = 0; ej < 4; ++ej) acc[ep][ej] += hvv[ep]*wvv[ej];
    }
    #pragma unroll
    for (int ep = 0; ep < 4; ++ep) {
        float4 o = {acc[ep][0],acc[ep][1],acc[ep][2],acc[ep][3]};
        *(float4*)&enc[(size_t)(P0+p0+ep)*128 + j0] = o;
    }
}

// mul = enc @ R[:, :10]; bin = argmax([mul, -mul]) first-max-wins; histogram
__global__ __launch_bounds__(256) void k_bins(const float* __restrict__ enc,
        const float* __restrict__ R, int* __restrict__ binIdx, int* __restrict__ hist) {
    __shared__ float Rl[128*10];
    const int tid = threadIdx.x;
    for (int idx = tid; idx < 1280; idx += 256) {
        int d = idx / 10, i = idx % 10;
        Rl[idx] = R[d*100 + i];
    }
    __syncthreads();
    int gp = blockIdx.x*256 + tid;
    if (gp >= TOTPTS) return;
    float acc[10];
    #pragma unroll
    for (int i = 0; i < 10; ++i) acc[i] = 0.f;
    const float4* er = (const float4*)(enc + (size_t)gp*128);
    for (int d4 = 0; d4 < 32; ++d4) {
        float4 e4 = er[d4];
        float ev[4] = {e4.x,e4.y,e4.z,e4.w};
        #pragma unroll
        for (int q = 0; q < 4; ++q) {
            const float* rr = &Rl[(d4*4+q)*10];
            #pragma unroll
            for (int i = 0; i < 10; ++i) acc[i] += ev[q]*rr[i];
        }
    }
    float best = acc[0]; int bi = 0;
    #pragma unroll
    for (int i = 1; i < 10; ++i) if (acc[i] > best) { best = acc[i]; bi = i; }
    #pragma unroll
    for (int i = 0; i < 10; ++i) { float v = -acc[i]; if (v > best) { best = v; bi = 10+i; } }
    binIdx[gp] = bi;
    atomicAdd(&hist[(gp/NPTS)*NBINS + bi], 1);
}

// stable counting-sort scatter: one block per (batch,bin)
__global__ __launch_bounds__(256) void k_sort(const int* __restrict__ binIdx,
        const int* __restrict__ hist, int* __restrict__ sortedIdx) {
    const int b = blockIdx.x / NBINS;
    const int bin = blockIdx.x % NBINS;
    const int tid = threadIdx.x;
    __shared__ int wtot[4];
    int off = 0;
    for (int k = 0; k < bin; ++k) off += hist[b*NBINS + k];
    const int* bptr = binIdx + b*NPTS;
    int* sptr = sortedIdx + b*NPTS;
    const int lane = tid & 63, wid = tid >> 6;
    for (int c = 0; c < 40; ++c) {
        int i = c*256 + tid;
        bool pred = (i < NPTS) && (bptr[i] == bin);
        unsigned long long mask = __ballot(pred);
        int rank = __popcll(mask & ((1ULL << lane) - 1ULL));
        if (lane == 0) wtot[wid] = __popcll(mask);
        __syncthreads();
        int prefix = 0;
        #pragma unroll
        for (int w = 0; w < 4; ++w) prefix += (w < wid) ? wtot[w] : 0;
        int total = wtot[0]+wtot[1]+wtot[2]+wtot[3];
        if (pred) sptr[off + prefix + rank] = i;
        off += total;
        __syncthreads();
    }
}

// insert (v,p) into sorted-desc 5-list, strict > (candidates arrive ascending p)
#define INS_STRICT(VV,PP,v,p) do { \
  if ((v) > VV[4]) { \
    if ((v) > VV[3]) { VV[4]=VV[3]; PP[4]=PP[3]; \
      if ((v) > VV[2]) { VV[3]=VV[2]; PP[3]=PP[2]; \
        if ((v) > VV[1]) { VV[2]=VV[1]; PP[2]=PP[1]; \
          if ((v) > VV[0]) { VV[1]=VV[0]; PP[1]=PP[0]; VV[0]=(v); PP[0]=(p); } \
          else { VV[1]=(v); PP[1]=(p); } } \
        else { VV[2]=(v); PP[2]=(p); } } \
      else { VV[3]=(v); PP[3]=(p); } } \
    else { VV[4]=(v); PP[4]=(p); } } } while(0)

// tie-aware better-than: (v desc, p asc) — exact lax.top_k semantics
#define BT(va,pa,vb,pb) (((va) > (vb)) || (((va) == (vb)) && ((pa) < (pb))))
#define INS_TIE(VV,PP,v,p) do { \
  if (BT(v,p,VV[4],PP[4])) { \
    if (BT(v,p,VV[3],PP[3])) { VV[4]=VV[3]; PP[4]=PP[3]; \
      if (BT(v,p,VV[2],PP[2])) { VV[3]=VV[2]; PP[3]=PP[2]; \
        if (BT(v,p,VV[1],PP[1])) { VV[2]=VV[1]; PP[2]=PP[1]; \
          if (BT(v,p,VV[0],PP[0])) { VV[1]=VV[0]; PP[1]=PP[0]; VV[0]=(v); PP[0]=(p); } \
          else { VV[1]=(v); PP[1]=(p); } } \
        else { VV[2]=(v); PP[2]=(p); } } \
      else { VV[3]=(v); PP[3]=(p); } } \
    else { VV[4]=(v); PP[4]=(p); } } } while(0)

// Gram partial: 256 threads, 256x128 block tile, 8 rows x 16 cols per thread
// (0.75 B of LDS read per FMA vs 1.25 for the 4x16 tile — LDS pipe is the
// binding resource). blockIdx = unit*160 + grp, unit = rowTile*4 + ch with
// rowTile in {0,1}, ch in {0..3}; 8 units => same-group blocks share an XCD.
// acc[8][16] is expected to live in AGPRs (unified file, r6-verified pattern).
__global__ __launch_bounds__(256) void k_gram(const float* __restrict__ enc,
        const int* __restrict__ sortedIdx, float* __restrict__ pV, int* __restrict__ pP) {
    __shared__ __align__(16) float As[32][256];   // [k][row]     32 KB, no swizzle
    __shared__ __align__(16) float Bs[32][128];   // [k][col swz] 16 KB (r6 swizzle)
    __shared__ int gIdx[500];
    const int tid = threadIdx.x;
    const int unit = blockIdx.x / 160;      // rowTile*4 + ch
    const int grp  = blockIdx.x - unit*160;
    const int rowTile = unit >> 2, ch = unit & 3;
    const int b = grp / NBINS, g = grp - b*NBINS;
    const int tx = tid & 7;                 // col group: cols tx*16..tx*16+15
    const int ty = tid >> 3;                // row group 0..31: rows ty*8..ty*8+7
    for (int i = tid; i < 500; i += 256) gIdx[i] = sortedIdx[b*NPTS + g*500 + i];
    __syncthreads();

    const int rowBase = rowTile * 256;
    const int rotq = (tx >> 1) & 3;         // B bank-swizzle rotation (in quads)
    const size_t encBase = (size_t)b * NPTS * 128;
    // A staging: one thread per row (32 floats = 8 float4 per chunk)
    const float* encA = enc + encBase + (size_t)gIdx[min(rowBase + tid, 499)] * 128;
    // B staging: 2 threads per col, 16 floats each (identical to r6)
    const int bCol = tid >> 1;
    const int sKh  = (tid & 1) * 16;
    const float* encB = enc + encBase + (size_t)gIdx[min(ch*128 + bCol, 499)] * 128 + sKh;
    const int c_sw = (bCol & ~15) | (((bCol & 15) + 4*((bCol >> 5) & 3)) & 15);

    float acc[8][16];
    #pragma unroll
    for (int er = 0; er < 8; ++er)
        #pragma unroll
        for (int ec = 0; ec < 16; ++ec) acc[er][ec] = 0.f;

    #pragma unroll 1
    for (int kc = 0; kc < 128; kc += 32) {
        __syncthreads();   // previous chunk's LDS reads done
        { // stage A: row tid, k kc..kc+31 -> As[k][tid] (2-way bank alias = free)
            const float* eA = encA + kc;
            #pragma unroll
            for (int q = 0; q < 8; ++q) {
                float4 v = *(const float4*)(eA + q*4);
                As[q*4+0][tid]=v.x; As[q*4+1][tid]=v.y;
                As[q*4+2][tid]=v.z; As[q*4+3][tid]=v.w;
            }
        }
        { // stage B: 128 cols x 32 k (transpose, swizzled col slot) — r6 code
            const float* eB = encB + kc;
            float4 v0 = *(const float4*)(eB + 0);
            float4 v1 = *(const float4*)(eB + 4);
            float4 v2 = *(const float4*)(eB + 8);
            float4 v3 = *(const float4*)(eB + 12);
            Bs[sKh+ 0][c_sw]=v0.x; Bs[sKh+ 1][c_sw]=v0.y; Bs[sKh+ 2][c_sw]=v0.z; Bs[sKh+ 3][c_sw]=v0.w;
            Bs[sKh+ 4][c_sw]=v1.x; Bs[sKh+ 5][c_sw]=v1.y; Bs[sKh+ 6][c_sw]=v1.z; Bs[sKh+ 7][c_sw]=v1.w;
            Bs[sKh+ 8][c_sw]=v2.x; Bs[sKh+ 9][c_sw]=v2.y; Bs[sKh+10][c_sw]=v2.z; Bs[sKh+11][c_sw]=v2.w;
            Bs[sKh+12][c_sw]=v3.x; Bs[sKh+13][c_sw]=v3.y; Bs[sKh+14][c_sw]=v3.z; Bs[sKh+15][c_sw]=v3.w;
        }
        __syncthreads();
        #pragma unroll 4
        for (int k = 0; k < 32; ++k) {
            float4 a40 = *(const float4*)&As[k][ty*8 + 0];
            float4 a41 = *(const float4*)&As[k][ty*8 + 4];
            float av[8] = {a40.x,a40.y,a40.z,a40.w,a41.x,a41.y,a41.z,a41.w};
            #pragma unroll
            for (int j = 0; j < 4; ++j) {
                int q = (j + rotq) & 3;                      // de-swizzle
                float4 b4 = *(const float4*)&Bs[k][tx*16 + q*4];
                float bv[4] = {b4.x, b4.y, b4.z, b4.w};
                #pragma unroll
                for (int er = 0; er < 8; ++er)
                    #pragma unroll
                    for (int m = 0; m < 4; ++m)
                        acc[er][m + j*4] += av[er] * bv[m];
            }
        }
    }

    // per-row fold + tx-lane merge + write, one row at a time (caps reg pressure)
    #pragma unroll 1
    for (int er = 0; er < 8; ++er) {
        float lv[5]; int lp[5];
        #pragma unroll
        for (int j = 0; j < 5; ++j) { lv[j] = -3.4e38f; lp[j] = 0x7fffffff; }
        #pragma unroll
        for (int ec = 0; ec < 16; ++ec) {
            int cpos = ch*128 + tx*16 + ec;
            if (cpos < 500) INS_STRICT(lv, lp, acc[er][ec], cpos);
        }
        #pragma unroll
        for (int m = 1; m < 8; m <<= 1) {
            float pv[5]; int pp[5];
            #pragma unroll
            for (int j = 0; j < 5; ++j) {
                pv[j] = __shfl_xor(lv[j], m, 64);
                pp[j] = __shfl_xor(lp[j], m, 64);
            }
            #pragma unroll
            for (int j = 0; j < 5; ++j) INS_TIE(lv, lp, pv[j], pp[j]);
        }
        int rpos = rowBase + ty*8 + er;
        if (tx == 0 && rpos < 500) {
            int base = ((grp*4 + ch)*PROWS + rpos)*5;
            #pragma unroll
            for (int j = 0; j < 5; ++j) { pV[base+j] = lv[j]; pP[base+j] = lp[j]; }
        }
    }
}

// fused merge + edge MLP, 4 threads per src point (j-loop split in 32-chunks,
// pairwise shfl_xor sum — summation-order change only, within edge tolerance).
__global__ __launch_bounds__(256) void k_edge(const float* __restrict__ X,
        const float* __restrict__ W1, const float* __restrict__ b1,
        const float* __restrict__ W2, const float* __restrict__ b2,
        const float* __restrict__ pV, const int* __restrict__ pP,
        const int* __restrict__ sortedIdx, float* __restrict__ out) {
    __shared__ float w1t[128*36];
    __shared__ float b1l[128];
    __shared__ float w2l[128];
    const int tid = threadIdx.x;
    for (int idx = tid; idx < 33*128; idx += 256) {
        int f = idx >> 7, j = idx & 127;
        w1t[j*36 + f] = W1[idx];
    }
    if (tid < 128) { b1l[tid] = b1[tid]; w2l[tid] = W2[tid]; }
    __syncthreads();
    int rid4 = blockIdx.x*256 + tid;
    if (rid4 >= NGRP*BINSZ*4) return;
    const int rid = rid4 >> 2, quarter = rid4 & 3;
    const int grp = rid / BINSZ;
    const int rowLocal = rid - grp*BINSZ;
    const int b = grp / NBINS, g = grp - b*NBINS;
    // ---- merge 4 ch-partials (duplicated across the 4 quarters; deterministic) ----
    float lv[5]; int lp[5];
    {
        int pbase = (grp*4*PROWS + rowLocal)*5;
        #pragma unroll
        for (int j = 0; j < 5; ++j) { lv[j] = pV[pbase+j]; lp[j] = pP[pbase+j]; }
    }
    #pragma unroll
    for (int chh = 1; chh < 4; ++chh) {
        int pbase = ((grp*4 + chh)*PROWS + rowLocal)*5;
        #pragma unroll
        for (int j = 0; j < 5; ++j) {
            float v = pV[pbase+j]; int p = pP[pbase+j];
            INS_TIE(lv, lp, v, p);
        }
    }
    const int* sIdx = sortedIdx + b*NPTS + g*BINSZ;
    const int src = sIdx[rowLocal];
    int dd[5]; float vv[5];
    #pragma unroll
    for (int j = 0; j < 5; ++j) {
        dd[j] = sIdx[lp[j]];
        vv[j] = 1.f/(1.f + expf(-lv[j]));
    }
    #define CSWAP(i,j) { if (dd[i] > dd[j]) { int td=dd[i];dd[i]=dd[j];dd[j]=td; \
                         float tf=vv[i];vv[i]=vv[j];vv[j]=tf; } }
    CSWAP(0,1) CSWAP(3,4) CSWAP(2,4) CSWAP(2,3) CSWAP(1,4)
    CSWAP(0,3) CSWAP(0,2) CSWAP(1,3) CSWAP(1,2)
    #undef CSWAP
    const int base = b*EDGES_PER_BATCH + src*5;
    if (quarter == 0) {
        #pragma unroll
        for (int e = 0; e < 5; ++e) {
            out[EDGE_TOT   + base + e] = (float)src;
            out[2*EDGE_TOT + base + e] = (float)dd[e];
        }
    }
    // ---- edge MLP over j-range [quarter*32, quarter*32+32) ----
    float4 xs[4];
    {
        const float4* xp = (const float4*)(X + ((size_t)b*NPTS + src)*NFEAT);
        #pragma unroll
        for (int q = 0; q < 4; ++q) xs[q] = xp[q];
    }
    float4 xd[5][4];
    #pragma unroll
    for (int e = 0; e < 5; ++e) {
        const float4* xp = (const float4*)(X + ((size_t)b*NPTS + dd[e])*NFEAT);
        #pragma unroll
        for (int q = 0; q < 4; ++q) xd[e][q] = xp[q];
    }
    float acc[5] = {0.f,0.f,0.f,0.f,0.f};
    const int jEnd = quarter*32 + 32;
    for (int j = quarter*32; j < jEnd; ++j) {
        const float* wr = &w1t[j*36];
        float4 ws0 = ((const float4*)wr)[0];
        float4 ws1 = ((const float4*)wr)[1];
        float4 ws2 = ((const float4*)wr)[2];
        float4 ws3 = ((const float4*)wr)[3];
        float4 u0  = ((const float4*)(wr+16))[0];
        float4 u1  = ((const float4*)(wr+16))[1];
        float4 u2  = ((const float4*)(wr+16))[2];
        float4 u3  = ((const float4*)(wr+16))[3];
        float w32 = wr[32];
        float w2j = w2l[j];
        float sh = b1l[j]
            + xs[0].x*ws0.x + xs[0].y*ws0.y + xs[0].z*ws0.z + xs[0].w*ws0.w
            + xs[1].x*ws1.x + xs[1].y*ws1.y + xs[1].z*ws1.z + xs[1].w*ws1.w
            + xs[2].x*ws2.x + xs[2].y*ws2.y + xs[2].z*ws2.z + xs[2].w*ws2.w
            + xs[3].x*ws3.x + xs[3].y*ws3.y + xs[3].z*ws3.z + xs[3].w*ws3.w;
        #pragma unroll
        for (int e = 0; e < 5; ++e) {
            float h = sh
                + xd[e][0].x*u0.x + xd[e][0].y*u0.y + xd[e][0].z*u0.z + xd[e][0].w*u0.w
                + xd[e][1].x*u1.x + xd[e][1].y*u1.y + xd[e][1].z*u1.z + xd[e][1].w*u1.w
                + xd[e][2].x*u2.x + xd[e][2].y*u2.y + xd[e][2].z*u2.z + xd[e][2].w*u2.w
                + xd[e][3].x*u3.x + xd[e][3].y*u3.y + xd[e][3].z*u3.z + xd[e][3].w*u3.w;
            h += vv[e]*w32;
            h = (h > 0.f) ? h : expm1f(h);
            acc[e] += h * w2j;
        }
    }
    // pairwise reduce across the 4 quarters: ((q0+q1)+(q2+q3))
    #pragma unroll
    for (int e = 0; e < 5; ++e) {
        acc[e] += __shfl_xor(acc[e], 1, 64);
        acc[e] += __shfl_xor(acc[e], 2, 64);
    }
    if (quarter != 0) return;
    float b2v = b2[0];
    #pragma unroll
    for (int e = 0; e < 5; ++e) {
        out[base + e] = 1.f/(1.f + expf(-(acc[e] + b2v)));
    }
}

extern "C" void kernel_launch(void* const* d_in, const int* in_sizes, int n_in,
                              void* d_out, int out_size, void* d_ws, size_t ws_size,
                              hipStream_t stream) {
    const float* X   = (const float*)d_in[0];
    const float* We1 = (const float*)d_in[1];
    const float* be1 = (const float*)d_in[2];
    const float* We2 = (const float*)d_in[3];
    const float* be2 = (const float*)d_in[4];
    const float* Wd1 = (const float*)d_in[5];
    const float* bd1 = (const float*)d_in[6];
    const float* Wd2 = (const float*)d_in[7];
    const float* bd2 = (const float*)d_in[8];
    const float* R   = (const float*)d_in[9];
    float* out = (float*)d_out;

    // workspace layout (~54 MB)
    float* enc      = (float*)d_ws;                       // 80000*128 f32
    int*   binIdx   = (int*)(enc + (size_t)TOTPTS*128);   // 80000
    int*   sortedIdx= binIdx + TOTPTS;                    // 80000
    int*   hist     = sortedIdx + TOTPTS;                 // 160
    float* pV       = (float*)(hist + NBATCH*NBINS);      // 160*4*512*5 = 1638400
    int*   pP       = (int*)(pV + (size_t)NGRP*4*PROWS*5);// 1638400

    k_enc  <<<TOTPTS/32, 256, 0, stream>>>(X, We1, be1, We2, be2, enc, hist);
    k_bins <<<(TOTPTS+255)/256, 256, 0, stream>>>(enc, R, binIdx, hist);
    k_sort <<<NBATCH*NBINS, 256, 0, stream>>>(binIdx, hist, sortedIdx);
    k_gram <<<NGRP*8, 256, 0, stream>>>(enc, sortedIdx, pV, pP);
    k_edge <<<(NGRP*BINSZ*4+255)/256, 256, 0, stream>>>(X, Wd1, bd1, Wd2, bd2,
                                                        pV, pP, sortedIdx, out);
}

// Round 9
// 642.424 us; speedup vs baseline: 1.1861x; 1.1861x over previous
//
#include <hip/hip_runtime.h>
#include <cmath>

#define NPTS 10000
#define NBATCH 8
#define NFEAT 16
#define DDIM 128
#define NBINS 20
#define BINSZ 500
#define KSEL 5
#define EDGES_PER_BATCH (NPTS*KSEL)        // 50000
#define EDGE_TOT (NBATCH*EDGES_PER_BATCH)  // 400000
#define TOTPTS (NBATCH*NPTS)               // 80000
#define NGRP (NBATCH*NBINS)                // 160
#define PROWS 512                          // padded rows per (grp,ch) partial slab

// enc = ELU(X@W1+b1)@W2+b2 ; 32 points per block, 256 threads.
// Block 0 also zeroes the bin histogram (k_bins runs after k_enc completes).
__global__ __launch_bounds__(256) void k_enc(const float* __restrict__ X,
        const float* __restrict__ W1, const float* __restrict__ b1,
        const float* __restrict__ W2, const float* __restrict__ b2,
        float* __restrict__ enc, int* __restrict__ hist) {
    __shared__ float hT[128*36];
    const int tid = threadIdx.x;
    const int P0 = blockIdx.x * 32;
    if (blockIdx.x == 0 && tid < NBATCH*NBINS) hist[tid] = 0;
    #pragma unroll
    for (int i = 0; i < 16; ++i) {
        int idx = i*256 + tid;
        int p = idx >> 7;
        int j = idx & 127;
        const float* xr = X + (size_t)(P0 + p)*NFEAT;
        float h = b1[j];
        #pragma unroll
        for (int f = 0; f < 16; ++f) h += xr[f] * W1[f*128 + j];
        h = (h > 0.f) ? h : expm1f(h);
        hT[j*36 + p] = h;
    }
    __syncthreads();
    const int jt = tid & 31, pt = tid >> 5;
    const int j0 = jt*4, p0 = pt*4;
    float acc[4][4];
    #pragma unroll
    for (int ep = 0; ep < 4; ++ep)
        #pragma unroll
        for (int ej = 0; ej < 4; ++ej) acc[ep][ej] = b2[j0+ej];
    for (int k = 0; k < 128; ++k) {
        float4 hv = *(const float4*)&hT[k*36 + p0];
        float4 wv = *(const float4*)&W2[k*128 + j0];
        float hvv[4] = {hv.x,hv.y,hv.z,hv.w};
        float wvv[4] = {wv.x,wv.y,wv.z,wv.w};
        #pragma unroll
        for (int ep = 0; ep < 4; ++ep)
            #pragma unroll
            for (int ej = 0; ej < 4; ++ej) acc[ep][ej] += hvv[ep]*wvv[ej];
    }
    #pragma unroll
    for (int ep = 0; ep < 4; ++ep) {
        float4 o = {acc[ep][0],acc[ep][1],acc[ep][2],acc[ep][3]};
        *(float4*)&enc[(size_t)(P0+p0+ep)*128 + j0] = o;
    }
}

// mul = enc @ R[:, :10]; bin = argmax([mul, -mul]) first-max-wins; histogram
__global__ __launch_bounds__(256) void k_bins(const float* __restrict__ enc,
        const float* __restrict__ R, int* __restrict__ binIdx, int* __restrict__ hist) {
    __shared__ float Rl[128*10];
    const int tid = threadIdx.x;
    for (int idx = tid; idx < 1280; idx += 256) {
        int d = idx / 10, i = idx % 10;
        Rl[idx] = R[d*100 + i];
    }
    __syncthreads();
    int gp = blockIdx.x*256 + tid;
    if (gp >= TOTPTS) return;
    float acc[10];
    #pragma unroll
    for (int i = 0; i < 10; ++i) acc[i] = 0.f;
    const float4* er = (const float4*)(enc + (size_t)gp*128);
    for (int d4 = 0; d4 < 32; ++d4) {
        float4 e4 = er[d4];
        float ev[4] = {e4.x,e4.y,e4.z,e4.w};
        #pragma unroll
        for (int q = 0; q < 4; ++q) {
            const float* rr = &Rl[(d4*4+q)*10];
            #pragma unroll
            for (int i = 0; i < 10; ++i) acc[i] += ev[q]*rr[i];
        }
    }
    float best = acc[0]; int bi = 0;
    #pragma unroll
    for (int i = 1; i < 10; ++i) if (acc[i] > best) { best = acc[i]; bi = i; }
    #pragma unroll
    for (int i = 0; i < 10; ++i) { float v = -acc[i]; if (v > best) { best = v; bi = 10+i; } }
    binIdx[gp] = bi;
    atomicAdd(&hist[(gp/NPTS)*NBINS + bi], 1);
}

// stable counting-sort scatter: one block per (batch,bin)
__global__ __launch_bounds__(256) void k_sort(const int* __restrict__ binIdx,
        const int* __restrict__ hist, int* __restrict__ sortedIdx) {
    const int b = blockIdx.x / NBINS;
    const int bin = blockIdx.x % NBINS;
    const int tid = threadIdx.x;
    __shared__ int wtot[4];
    int off = 0;
    for (int k = 0; k < bin; ++k) off += hist[b*NBINS + k];
    const int* bptr = binIdx + b*NPTS;
    int* sptr = sortedIdx + b*NPTS;
    const int lane = tid & 63, wid = tid >> 6;
    for (int c = 0; c < 40; ++c) {
        int i = c*256 + tid;
        bool pred = (i < NPTS) && (bptr[i] == bin);
        unsigned long long mask = __ballot(pred);
        int rank = __popcll(mask & ((1ULL << lane) - 1ULL));
        if (lane == 0) wtot[wid] = __popcll(mask);
        __syncthreads();
        int prefix = 0;
        #pragma unroll
        for (int w = 0; w < 4; ++w) prefix += (w < wid) ? wtot[w] : 0;
        int total = wtot[0]+wtot[1]+wtot[2]+wtot[3];
        if (pred) sptr[off + prefix + rank] = i;
        off += total;
        __syncthreads();
    }
}

// insert (v,p) into sorted-desc 5-list, strict > (candidates arrive ascending p)
#define INS_STRICT(VV,PP,v,p) do { \
  if ((v) > VV[4]) { \
    if ((v) > VV[3]) { VV[4]=VV[3]; PP[4]=PP[3]; \
      if ((v) > VV[2]) { VV[3]=VV[2]; PP[3]=PP[2]; \
        if ((v) > VV[1]) { VV[2]=VV[1]; PP[2]=PP[1]; \
          if ((v) > VV[0]) { VV[1]=VV[0]; PP[1]=PP[0]; VV[0]=(v); PP[0]=(p); } \
          else { VV[1]=(v); PP[1]=(p); } } \
        else { VV[2]=(v); PP[2]=(p); } } \
      else { VV[3]=(v); PP[3]=(p); } } \
    else { VV[4]=(v); PP[4]=(p); } } } while(0)

// tie-aware better-than: (v desc, p asc) — exact lax.top_k semantics
#define BT(va,pa,vb,pb) (((va) > (vb)) || (((va) == (vb)) && ((pa) < (pb))))
#define INS_TIE(VV,PP,v,p) do { \
  if (BT(v,p,VV[4],PP[4])) { \
    if (BT(v,p,VV[3],PP[3])) { VV[4]=VV[3]; PP[4]=PP[3]; \
      if (BT(v,p,VV[2],PP[2])) { VV[3]=VV[2]; PP[3]=PP[2]; \
        if (BT(v,p,VV[1],PP[1])) { VV[2]=VV[1]; PP[2]=PP[1]; \
          if (BT(v,p,VV[0],PP[0])) { VV[1]=VV[0]; PP[1]=PP[0]; VV[0]=(v); PP[0]=(p); } \
          else { VV[1]=(v); PP[1]=(p); } } \
        else { VV[2]=(v); PP[2]=(p); } } \
      else { VV[3]=(v); PP[3]=(p); } } \
    else { VV[4]=(v); PP[4]=(p); } } } while(0)

// Gram partial: 256 threads, 128x128 block tile, 8 rows x 8 cols per thread
// (64 accumulators — the r6-proven no-spill budget — but 4 ds_read_b128 per
// 64 FMA instead of 5; A reads are 16-lane broadcasts). Staging and LDS
// layout byte-identical to r6. blockIdx = unit*160 + grp (XCD-aligned, r3).
__global__ __launch_bounds__(256) void k_gram(const float* __restrict__ enc,
        const int* __restrict__ sortedIdx, float* __restrict__ pV, int* __restrict__ pP) {
    __shared__ __align__(16) float As[32][128];   // [k][row]     16 KB
    __shared__ __align__(16) float Bs[32][128];   // [k][col swz] 16 KB
    __shared__ int gIdx[500];
    const int tid = threadIdx.x;
    const int unit = blockIdx.x / 160;      // rowTile*4 + ch
    const int grp  = blockIdx.x - unit*160;
    const int rowTile = unit >> 2, ch = unit & 3;
    const int b = grp / NBINS, g = grp - b*NBINS;
    const int tx = tid & 15;                // col group: cols tx*8..tx*8+7
    const int ty = tid >> 4;                // row group 0..15: rows ty*8..ty*8+7
    for (int i = tid; i < 500; i += 256) gIdx[i] = sortedIdx[b*NPTS + g*500 + i];
    __syncthreads();

    const int rowBase = rowTile * 128;
    const size_t encBase = (size_t)b * NPTS * 128;
    const int sRow = tid >> 1;              // A staging: row 0..127 (2 thr/row)
    const int sKh  = (tid & 1) * 16;        // staging k-half
    const float* encA = enc + encBase + (size_t)gIdx[min(rowBase + sRow, 499)] * 128 + sKh;
    const int bCol = tid >> 1;              // B staging: col 0..127 (2 thr/col)
    const float* encB = enc + encBase + (size_t)gIdx[min(ch*128 + bCol, 499)] * 128 + sKh;
    // B col slot swizzle (identical to r6): rotate quads within 16-slot group
    const int c_sw = (bCol & ~15) | (((bCol & 15) + 4*((bCol >> 5) & 3)) & 15);
    // de-swizzle constants for the 8x8 read pattern:
    const int bCont = (tx >> 1) * 16;       // 16-slot container base
    const int bRot  = (tx >> 2) & 3;        // quad rotation of my container half
    const int bO    = (tx & 1) * 2;         // my logical quad offset (0 or 2)

    float acc[8][8];
    #pragma unroll
    for (int er = 0; er < 8; ++er)
        #pragma unroll
        for (int ec = 0; ec < 8; ++ec) acc[er][ec] = 0.f;

    #pragma unroll 1
    for (int kc = 0; kc < 128; kc += 32) {
        __syncthreads();   // previous chunk's LDS reads done
        { // stage A: 128 rows x 32 k (transpose to [k][row]) — r6 code
            const float* eA = encA + kc;
            float4 v0 = *(const float4*)(eA + 0);
            float4 v1 = *(const float4*)(eA + 4);
            float4 v2 = *(const float4*)(eA + 8);
            float4 v3 = *(const float4*)(eA + 12);
            As[sKh+ 0][sRow]=v0.x; As[sKh+ 1][sRow]=v0.y; As[sKh+ 2][sRow]=v0.z; As[sKh+ 3][sRow]=v0.w;
            As[sKh+ 4][sRow]=v1.x; As[sKh+ 5][sRow]=v1.y; As[sKh+ 6][sRow]=v1.z; As[sKh+ 7][sRow]=v1.w;
            As[sKh+ 8][sRow]=v2.x; As[sKh+ 9][sRow]=v2.y; As[sKh+10][sRow]=v2.z; As[sKh+11][sRow]=v2.w;
            As[sKh+12][sRow]=v3.x; As[sKh+13][sRow]=v3.y; As[sKh+14][sRow]=v3.z; As[sKh+15][sRow]=v3.w;
        }
        { // stage B: 128 cols x 32 k (transpose, swizzled col slot) — r6 code
            const float* eB = encB + kc;
            float4 v0 = *(const float4*)(eB + 0);
            float4 v1 = *(const float4*)(eB + 4);
            float4 v2 = *(const float4*)(eB + 8);
            float4 v3 = *(const float4*)(eB + 12);
            Bs[sKh+ 0][c_sw]=v0.x; Bs[sKh+ 1][c_sw]=v0.y; Bs[sKh+ 2][c_sw]=v0.z; Bs[sKh+ 3][c_sw]=v0.w;
            Bs[sKh+ 4][c_sw]=v1.x; Bs[sKh+ 5][c_sw]=v1.y; Bs[sKh+ 6][c_sw]=v1.z; Bs[sKh+ 7][c_sw]=v1.w;
            Bs[sKh+ 8][c_sw]=v2.x; Bs[sKh+ 9][c_sw]=v2.y; Bs[sKh+10][c_sw]=v2.z; Bs[sKh+11][c_sw]=v2.w;
            Bs[sKh+12][c_sw]=v3.x; Bs[sKh+13][c_sw]=v3.y; Bs[sKh+14][c_sw]=v3.z; Bs[sKh+15][c_sw]=v3.w;
        }
        __syncthreads();
        #pragma unroll 4
        for (int k = 0; k < 32; ++k) {
            float4 a40 = *(const float4*)&As[k][ty*8 + 0];   // broadcast (16 lanes)
            float4 a41 = *(const float4*)&As[k][ty*8 + 4];
            float av[8] = {a40.x,a40.y,a40.z,a40.w,a41.x,a41.y,a41.z,a41.w};
            #pragma unroll
            for (int q = 0; q < 2; ++q) {
                int p = ((bO + q + bRot) & 3) * 4;           // de-swizzled quad
                float4 b4 = *(const float4*)&Bs[k][bCont + p];
                float bv[4] = {b4.x, b4.y, b4.z, b4.w};
                #pragma unroll
                for (int er = 0; er < 8; ++er)
                    #pragma unroll
                    for (int m = 0; m < 4; ++m)
                        acc[er][q*4 + m] += av[er] * bv[m];
            }
        }
    }

    // per-row fold + 16-lane tx merge + write, one row at a time
    #pragma unroll 1
    for (int er = 0; er < 8; ++er) {
        float lv[5]; int lp[5];
        #pragma unroll
        for (int j = 0; j < 5; ++j) { lv[j] = -3.4e38f; lp[j] = 0x7fffffff; }
        #pragma unroll
        for (int ec = 0; ec < 8; ++ec) {
            int cpos = ch*128 + tx*8 + ec;
            if (cpos < 500) INS_STRICT(lv, lp, acc[er][ec], cpos);
        }
        #pragma unroll
        for (int m = 1; m < 16; m <<= 1) {
            float pv[5]; int pp[5];
            #pragma unroll
            for (int j = 0; j < 5; ++j) {
                pv[j] = __shfl_xor(lv[j], m, 64);
                pp[j] = __shfl_xor(lp[j], m, 64);
            }
            #pragma unroll
            for (int j = 0; j < 5; ++j) INS_TIE(lv, lp, pv[j], pp[j]);
        }
        int rpos = rowBase + ty*8 + er;
        if (tx == 0 && rpos < 500) {
            int base = ((grp*4 + ch)*PROWS + rpos)*5;
            #pragma unroll
            for (int j = 0; j < 5; ++j) { pV[base+j] = lv[j]; pP[base+j] = lp[j]; }
        }
    }
}

// fused merge + edge MLP, 4 threads per src point (j-loop split in 32-chunks,
// pairwise shfl_xor sum — summation-order change only, within edge tolerance).
__global__ __launch_bounds__(256) void k_edge(const float* __restrict__ X,
        const float* __restrict__ W1, const float* __restrict__ b1,
        const float* __restrict__ W2, const float* __restrict__ b2,
        const float* __restrict__ pV, const int* __restrict__ pP,
        const int* __restrict__ sortedIdx, float* __restrict__ out) {
    __shared__ float w1t[128*36];
    __shared__ float b1l[128];
    __shared__ float w2l[128];
    const int tid = threadIdx.x;
    for (int idx = tid; idx < 33*128; idx += 256) {
        int f = idx >> 7, j = idx & 127;
        w1t[j*36 + f] = W1[idx];
    }
    if (tid < 128) { b1l[tid] = b1[tid]; w2l[tid] = W2[tid]; }
    __syncthreads();
    int rid4 = blockIdx.x*256 + tid;
    if (rid4 >= NGRP*BINSZ*4) return;
    const int rid = rid4 >> 2, quarter = rid4 & 3;
    const int grp = rid / BINSZ;
    const int rowLocal = rid - grp*BINSZ;
    const int b = grp / NBINS, g = grp - b*NBINS;
    // ---- merge 4 ch-partials (duplicated across the 4 quarters; deterministic) ----
    float lv[5]; int lp[5];
    {
        int pbase = (grp*4*PROWS + rowLocal)*5;
        #pragma unroll
        for (int j = 0; j < 5; ++j) { lv[j] = pV[pbase+j]; lp[j] = pP[pbase+j]; }
    }
    #pragma unroll
    for (int chh = 1; chh < 4; ++chh) {
        int pbase = ((grp*4 + chh)*PROWS + rowLocal)*5;
        #pragma unroll
        for (int j = 0; j < 5; ++j) {
            float v = pV[pbase+j]; int p = pP[pbase+j];
            INS_TIE(lv, lp, v, p);
        }
    }
    const int* sIdx = sortedIdx + b*NPTS + g*BINSZ;
    const int src = sIdx[rowLocal];
    int dd[5]; float vv[5];
    #pragma unroll
    for (int j = 0; j < 5; ++j) {
        dd[j] = sIdx[lp[j]];
        vv[j] = 1.f/(1.f + expf(-lv[j]));
    }
    #define CSWAP(i,j) { if (dd[i] > dd[j]) { int td=dd[i];dd[i]=dd[j];dd[j]=td; \
                         float tf=vv[i];vv[i]=vv[j];vv[j]=tf; } }
    CSWAP(0,1) CSWAP(3,4) CSWAP(2,4) CSWAP(2,3) CSWAP(1,4)
    CSWAP(0,3) CSWAP(0,2) CSWAP(1,3) CSWAP(1,2)
    #undef CSWAP
    const int base = b*EDGES_PER_BATCH + src*5;
    if (quarter == 0) {
        #pragma unroll
        for (int e = 0; e < 5; ++e) {
            out[EDGE_TOT   + base + e] = (float)src;
            out[2*EDGE_TOT + base + e] = (float)dd[e];
        }
    }
    // ---- edge MLP over j-range [quarter*32, quarter*32+32) ----
    float4 xs[4];
    {
        const float4* xp = (const float4*)(X + ((size_t)b*NPTS + src)*NFEAT);
        #pragma unroll
        for (int q = 0; q < 4; ++q) xs[q] = xp[q];
    }
    float4 xd[5][4];
    #pragma unroll
    for (int e = 0; e < 5; ++e) {
        const float4* xp = (const float4*)(X + ((size_t)b*NPTS + dd[e])*NFEAT);
        #pragma unroll
        for (int q = 0; q < 4; ++q) xd[e][q] = xp[q];
    }
    float acc[5] = {0.f,0.f,0.f,0.f,0.f};
    const int jEnd = quarter*32 + 32;
    for (int j = quarter*32; j < jEnd; ++j) {
        const float* wr = &w1t[j*36];
        float4 ws0 = ((const float4*)wr)[0];
        float4 ws1 = ((const float4*)wr)[1];
        float4 ws2 = ((const float4*)wr)[2];
        float4 ws3 = ((const float4*)wr)[3];
        float4 u0  = ((const float4*)(wr+16))[0];
        float4 u1  = ((const float4*)(wr+16))[1];
        float4 u2  = ((const float4*)(wr+16))[2];
        float4 u3  = ((const float4*)(wr+16))[3];
        float w32 = wr[32];
        float w2j = w2l[j];
        float sh = b1l[j]
            + xs[0].x*ws0.x + xs[0].y*ws0.y + xs[0].z*ws0.z + xs[0].w*ws0.w
            + xs[1].x*ws1.x + xs[1].y*ws1.y + xs[1].z*ws1.z + xs[1].w*ws1.w
            + xs[2].x*ws2.x + xs[2].y*ws2.y + xs[2].z*ws2.z + xs[2].w*ws2.w
            + xs[3].x*ws3.x + xs[3].y*ws3.y + xs[3].z*ws3.z + xs[3].w*ws3.w;
        #pragma unroll
        for (int e = 0; e < 5; ++e) {
            float h = sh
                + xd[e][0].x*u0.x + xd[e][0].y*u0.y + xd[e][0].z*u0.z + xd[e][0].w*u0.w
                + xd[e][1].x*u1.x + xd[e][1].y*u1.y + xd[e][1].z*u1.z + xd[e][1].w*u1.w
                + xd[e][2].x*u2.x + xd[e][2].y*u2.y + xd[e][2].z*u2.z + xd[e][2].w*u2.w
                + xd[e][3].x*u3.x + xd[e][3].y*u3.y + xd[e][3].z*u3.z + xd[e][3].w*u3.w;
            h += vv[e]*w32;
            h = (h > 0.f) ? h : expm1f(h);
            acc[e] += h * w2j;
        }
    }
    // pairwise reduce across the 4 quarters: ((q0+q1)+(q2+q3))
    #pragma unroll
    for (int e = 0; e < 5; ++e) {
        acc[e] += __shfl_xor(acc[e], 1, 64);
        acc[e] += __shfl_xor(acc[e], 2, 64);
    }
    if (quarter != 0) return;
    float b2v = b2[0];
    #pragma unroll
    for (int e = 0; e < 5; ++e) {
        out[base + e] = 1.f/(1.f + expf(-(acc[e] + b2v)));
    }
}

extern "C" void kernel_launch(void* const* d_in, const int* in_sizes, int n_in,
                              void* d_out, int out_size, void* d_ws, size_t ws_size,
                              hipStream_t stream) {
    const float* X   = (const float*)d_in[0];
    const float* We1 = (const float*)d_in[1];
    const float* be1 = (const float*)d_in[2];
    const float* We2 = (const float*)d_in[3];
    const float* be2 = (const float*)d_in[4];
    const float* Wd1 = (const float*)d_in[5];
    const float* bd1 = (const float*)d_in[6];
    const float* Wd2 = (const float*)d_in[7];
    const float* bd2 = (const float*)d_in[8];
    const float* R   = (const float*)d_in[9];
    float* out = (float*)d_out;

    // workspace layout (~54 MB)
    float* enc      = (float*)d_ws;                       // 80000*128 f32
    int*   binIdx   = (int*)(enc + (size_t)TOTPTS*128);   // 80000
    int*   sortedIdx= binIdx + TOTPTS;                    // 80000
    int*   hist     = sortedIdx + TOTPTS;                 // 160
    float* pV       = (float*)(hist + NBATCH*NBINS);      // 160*4*512*5 = 1638400
    int*   pP       = (int*)(pV + (size_t)NGRP*4*PROWS*5);// 1638400

    k_enc  <<<TOTPTS/32, 256, 0, stream>>>(X, We1, be1, We2, be2, enc, hist);
    k_bins <<<(TOTPTS+255)/256, 256, 0, stream>>>(enc, R, binIdx, hist);
    k_sort <<<NBATCH*NBINS, 256, 0, stream>>>(binIdx, hist, sortedIdx);
    k_gram <<<NGRP*16, 256, 0, stream>>>(enc, sortedIdx, pV, pP);
    k_edge <<<(NGRP*BINSZ*4+255)/256, 256, 0, stream>>>(X, Wd1, bd1, Wd2, bd2,
                                                        pV, pP, sortedIdx, out);
}

// Round 10
// 574.933 us; speedup vs baseline: 1.3253x; 1.1174x over previous
//
#include <hip/hip_runtime.h>
#include <cmath>

#define NPTS 10000
#define NBATCH 8
#define NFEAT 16
#define DDIM 128
#define NBINS 20
#define BINSZ 500
#define KSEL 5
#define EDGES_PER_BATCH (NPTS*KSEL)        // 50000
#define EDGE_TOT (NBATCH*EDGES_PER_BATCH)  // 400000
#define TOTPTS (NBATCH*NPTS)               // 80000
#define NGRP (NBATCH*NBINS)                // 160
#define PROWS 512                          // padded rows per (grp,ch) partial slab

// enc = ELU(X@W1+b1)@W2+b2 ; 32 points per block, 256 threads.
// Block 0 also zeroes the bin histogram (k_bins runs after k_enc completes).
__global__ __launch_bounds__(256) void k_enc(const float* __restrict__ X,
        const float* __restrict__ W1, const float* __restrict__ b1,
        const float* __restrict__ W2, const float* __restrict__ b2,
        float* __restrict__ enc, int* __restrict__ hist) {
    __shared__ float hT[128*36];
    const int tid = threadIdx.x;
    const int P0 = blockIdx.x * 32;
    if (blockIdx.x == 0 && tid < NBATCH*NBINS) hist[tid] = 0;
    #pragma unroll
    for (int i = 0; i < 16; ++i) {
        int idx = i*256 + tid;
        int p = idx >> 7;
        int j = idx & 127;
        const float* xr = X + (size_t)(P0 + p)*NFEAT;
        float h = b1[j];
        #pragma unroll
        for (int f = 0; f < 16; ++f) h += xr[f] * W1[f*128 + j];
        h = (h > 0.f) ? h : expm1f(h);
        hT[j*36 + p] = h;
    }
    __syncthreads();
    const int jt = tid & 31, pt = tid >> 5;
    const int j0 = jt*4, p0 = pt*4;
    float acc[4][4];
    #pragma unroll
    for (int ep = 0; ep < 4; ++ep)
        #pragma unroll
        for (int ej = 0; ej < 4; ++ej) acc[ep][ej] = b2[j0+ej];
    for (int k = 0; k < 128; ++k) {
        float4 hv = *(const float4*)&hT[k*36 + p0];
        float4 wv = *(const float4*)&W2[k*128 + j0];
        float hvv[4] = {hv.x,hv.y,hv.z,hv.w};
        float wvv[4] = {wv.x,wv.y,wv.z,wv.w};
        #pragma unroll
        for (int ep = 0; ep < 4; ++ep)
            #pragma unroll
            for (int ej = 0; ej < 4; ++ej) acc[ep][ej] += hvv[ep]*wvv[ej];
    }
    #pragma unroll
    for (int ep = 0; ep < 4; ++ep) {
        float4 o = {acc[ep][0],acc[ep][1],acc[ep][2],acc[ep][3]};
        *(float4*)&enc[(size_t)(P0+p0+ep)*128 + j0] = o;
    }
}

// mul = enc @ R[:, :10]; bin = argmax([mul, -mul]) first-max-wins; histogram
__global__ __launch_bounds__(256) void k_bins(const float* __restrict__ enc,
        const float* __restrict__ R, int* __restrict__ binIdx, int* __restrict__ hist) {
    __shared__ float Rl[128*10];
    const int tid = threadIdx.x;
    for (int idx = tid; idx < 1280; idx += 256) {
        int d = idx / 10, i = idx % 10;
        Rl[idx] = R[d*100 + i];
    }
    __syncthreads();
    int gp = blockIdx.x*256 + tid;
    if (gp >= TOTPTS) return;
    float acc[10];
    #pragma unroll
    for (int i = 0; i < 10; ++i) acc[i] = 0.f;
    const float4* er = (const float4*)(enc + (size_t)gp*128);
    for (int d4 = 0; d4 < 32; ++d4) {
        float4 e4 = er[d4];
        float ev[4] = {e4.x,e4.y,e4.z,e4.w};
        #pragma unroll
        for (int q = 0; q < 4; ++q) {
            const float* rr = &Rl[(d4*4+q)*10];
            #pragma unroll
            for (int i = 0; i < 10; ++i) acc[i] += ev[q]*rr[i];
        }
    }
    float best = acc[0]; int bi = 0;
    #pragma unroll
    for (int i = 1; i < 10; ++i) if (acc[i] > best) { best = acc[i]; bi = i; }
    #pragma unroll
    for (int i = 0; i < 10; ++i) { float v = -acc[i]; if (v > best) { best = v; bi = 10+i; } }
    binIdx[gp] = bi;
    atomicAdd(&hist[(gp/NPTS)*NBINS + bi], 1);
}

// stable counting-sort scatter: one block per (batch,bin)
__global__ __launch_bounds__(256) void k_sort(const int* __restrict__ binIdx,
        const int* __restrict__ hist, int* __restrict__ sortedIdx) {
    const int b = blockIdx.x / NBINS;
    const int bin = blockIdx.x % NBINS;
    const int tid = threadIdx.x;
    __shared__ int wtot[4];
    int off = 0;
    for (int k = 0; k < bin; ++k) off += hist[b*NBINS + k];
    const int* bptr = binIdx + b*NPTS;
    int* sptr = sortedIdx + b*NPTS;
    const int lane = tid & 63, wid = tid >> 6;
    for (int c = 0; c < 40; ++c) {
        int i = c*256 + tid;
        bool pred = (i < NPTS) && (bptr[i] == bin);
        unsigned long long mask = __ballot(pred);
        int rank = __popcll(mask & ((1ULL << lane) - 1ULL));
        if (lane == 0) wtot[wid] = __popcll(mask);
        __syncthreads();
        int prefix = 0;
        #pragma unroll
        for (int w = 0; w < 4; ++w) prefix += (w < wid) ? wtot[w] : 0;
        int total = wtot[0]+wtot[1]+wtot[2]+wtot[3];
        if (pred) sptr[off + prefix + rank] = i;
        off += total;
        __syncthreads();
    }
}

// insert (v,p) into sorted-desc 5-list, strict > (candidates arrive ascending p)
#define INS_STRICT(VV,PP,v,p) do { \
  if ((v) > VV[4]) { \
    if ((v) > VV[3]) { VV[4]=VV[3]; PP[4]=PP[3]; \
      if ((v) > VV[2]) { VV[3]=VV[2]; PP[3]=PP[2]; \
        if ((v) > VV[1]) { VV[2]=VV[1]; PP[2]=PP[1]; \
          if ((v) > VV[0]) { VV[1]=VV[0]; PP[1]=PP[0]; VV[0]=(v); PP[0]=(p); } \
          else { VV[1]=(v); PP[1]=(p); } } \
        else { VV[2]=(v); PP[2]=(p); } } \
      else { VV[3]=(v); PP[3]=(p); } } \
    else { VV[4]=(v); PP[4]=(p); } } } while(0)

// tie-aware better-than: (v desc, p asc) — exact lax.top_k semantics
#define BT(va,pa,vb,pb) (((va) > (vb)) || (((va) == (vb)) && ((pa) < (pb))))
#define INS_TIE(VV,PP,v,p) do { \
  if (BT(v,p,VV[4],PP[4])) { \
    if (BT(v,p,VV[3],PP[3])) { VV[4]=VV[3]; PP[4]=PP[3]; \
      if (BT(v,p,VV[2],PP[2])) { VV[3]=VV[2]; PP[3]=PP[2]; \
        if (BT(v,p,VV[1],PP[1])) { VV[2]=VV[1]; PP[2]=PP[1]; \
          if (BT(v,p,VV[0],PP[0])) { VV[1]=VV[0]; PP[1]=PP[0]; VV[0]=(v); PP[0]=(p); } \
          else { VV[1]=(v); PP[1]=(p); } } \
        else { VV[2]=(v); PP[2]=(p); } } \
      else { VV[3]=(v); PP[3]=(p); } } \
    else { VV[4]=(v); PP[4]=(p); } } } while(0)

// Gram partial: 256 threads, 128x128 block tile, 8 rows x 8 cols per thread.
// 4 ds_read_b128 per 64 FMA (A reads broadcast). Fold is FULLY UNROLLED —
// any runtime index into acc[][] forces the array to scratch (r4/r8/r9 bug:
// WRITE_SIZE ballooned to ~850 MB from scratch spill of acc).
// blockIdx = unit*160 + grp (XCD-aligned, r3-verified).
__global__ __launch_bounds__(256) void k_gram(const float* __restrict__ enc,
        const int* __restrict__ sortedIdx, float* __restrict__ pV, int* __restrict__ pP) {
    __shared__ __align__(16) float As[32][128];   // [k][row]     16 KB
    __shared__ __align__(16) float Bs[32][128];   // [k][col swz] 16 KB
    __shared__ int gIdx[500];
    const int tid = threadIdx.x;
    const int unit = blockIdx.x / 160;      // rowTile*4 + ch
    const int grp  = blockIdx.x - unit*160;
    const int rowTile = unit >> 2, ch = unit & 3;
    const int b = grp / NBINS, g = grp - b*NBINS;
    const int tx = tid & 15;                // col group: cols tx*8..tx*8+7
    const int ty = tid >> 4;                // row group 0..15: rows ty*8..ty*8+7
    for (int i = tid; i < 500; i += 256) gIdx[i] = sortedIdx[b*NPTS + g*500 + i];
    __syncthreads();

    const int rowBase = rowTile * 128;
    const size_t encBase = (size_t)b * NPTS * 128;
    const int sRow = tid >> 1;              // A staging: row 0..127 (2 thr/row)
    const int sKh  = (tid & 1) * 16;        // staging k-half
    const float* encA = enc + encBase + (size_t)gIdx[min(rowBase + sRow, 499)] * 128 + sKh;
    const int bCol = tid >> 1;              // B staging: col 0..127 (2 thr/col)
    const float* encB = enc + encBase + (size_t)gIdx[min(ch*128 + bCol, 499)] * 128 + sKh;
    // B col slot swizzle (identical to r6): rotate quads within 16-slot group
    const int c_sw = (bCol & ~15) | (((bCol & 15) + 4*((bCol >> 5) & 3)) & 15);
    // de-swizzle constants for the 8x8 read pattern:
    const int bCont = (tx >> 1) * 16;       // 16-slot container base
    const int bRot  = (tx >> 2) & 3;        // quad rotation of my container half
    const int bO    = (tx & 1) * 2;         // my logical quad offset (0 or 2)

    float acc[8][8];
    #pragma unroll
    for (int er = 0; er < 8; ++er)
        #pragma unroll
        for (int ec = 0; ec < 8; ++ec) acc[er][ec] = 0.f;

    #pragma unroll 1
    for (int kc = 0; kc < 128; kc += 32) {
        __syncthreads();   // previous chunk's LDS reads done
        { // stage A: 128 rows x 32 k (transpose to [k][row]) — r6 code
            const float* eA = encA + kc;
            float4 v0 = *(const float4*)(eA + 0);
            float4 v1 = *(const float4*)(eA + 4);
            float4 v2 = *(const float4*)(eA + 8);
            float4 v3 = *(const float4*)(eA + 12);
            As[sKh+ 0][sRow]=v0.x; As[sKh+ 1][sRow]=v0.y; As[sKh+ 2][sRow]=v0.z; As[sKh+ 3][sRow]=v0.w;
            As[sKh+ 4][sRow]=v1.x; As[sKh+ 5][sRow]=v1.y; As[sKh+ 6][sRow]=v1.z; As[sKh+ 7][sRow]=v1.w;
            As[sKh+ 8][sRow]=v2.x; As[sKh+ 9][sRow]=v2.y; As[sKh+10][sRow]=v2.z; As[sKh+11][sRow]=v2.w;
            As[sKh+12][sRow]=v3.x; As[sKh+13][sRow]=v3.y; As[sKh+14][sRow]=v3.z; As[sKh+15][sRow]=v3.w;
        }
        { // stage B: 128 cols x 32 k (transpose, swizzled col slot) — r6 code
            const float* eB = encB + kc;
            float4 v0 = *(const float4*)(eB + 0);
            float4 v1 = *(const float4*)(eB + 4);
            float4 v2 = *(const float4*)(eB + 8);
            float4 v3 = *(const float4*)(eB + 12);
            Bs[sKh+ 0][c_sw]=v0.x; Bs[sKh+ 1][c_sw]=v0.y; Bs[sKh+ 2][c_sw]=v0.z; Bs[sKh+ 3][c_sw]=v0.w;
            Bs[sKh+ 4][c_sw]=v1.x; Bs[sKh+ 5][c_sw]=v1.y; Bs[sKh+ 6][c_sw]=v1.z; Bs[sKh+ 7][c_sw]=v1.w;
            Bs[sKh+ 8][c_sw]=v2.x; Bs[sKh+ 9][c_sw]=v2.y; Bs[sKh+10][c_sw]=v2.z; Bs[sKh+11][c_sw]=v2.w;
            Bs[sKh+12][c_sw]=v3.x; Bs[sKh+13][c_sw]=v3.y; Bs[sKh+14][c_sw]=v3.z; Bs[sKh+15][c_sw]=v3.w;
        }
        __syncthreads();
        #pragma unroll 4
        for (int k = 0; k < 32; ++k) {
            float4 a40 = *(const float4*)&As[k][ty*8 + 0];   // broadcast (16 lanes)
            float4 a41 = *(const float4*)&As[k][ty*8 + 4];
            float av[8] = {a40.x,a40.y,a40.z,a40.w,a41.x,a41.y,a41.z,a41.w};
            #pragma unroll
            for (int q = 0; q < 2; ++q) {
                int p = ((bO + q + bRot) & 3) * 4;           // de-swizzled quad
                float4 b4 = *(const float4*)&Bs[k][bCont + p];
                float bv[4] = {b4.x, b4.y, b4.z, b4.w};
                #pragma unroll
                for (int er = 0; er < 8; ++er)
                    #pragma unroll
                    for (int m = 0; m < 4; ++m)
                        acc[er][q*4 + m] += av[er] * bv[m];
            }
        }
    }

    // per-row fold + 16-lane tx merge + write — FULLY UNROLLED (constant er!)
    #pragma unroll
    for (int er = 0; er < 8; ++er) {
        float lv[5]; int lp[5];
        #pragma unroll
        for (int j = 0; j < 5; ++j) { lv[j] = -3.4e38f; lp[j] = 0x7fffffff; }
        #pragma unroll
        for (int ec = 0; ec < 8; ++ec) {
            int cpos = ch*128 + tx*8 + ec;
            if (cpos < 500) INS_STRICT(lv, lp, acc[er][ec], cpos);
        }
        #pragma unroll
        for (int m = 1; m < 16; m <<= 1) {
            float pv[5]; int pp[5];
            #pragma unroll
            for (int j = 0; j < 5; ++j) {
                pv[j] = __shfl_xor(lv[j], m, 64);
                pp[j] = __shfl_xor(lp[j], m, 64);
            }
            #pragma unroll
            for (int j = 0; j < 5; ++j) INS_TIE(lv, lp, pv[j], pp[j]);
        }
        int rpos = rowBase + ty*8 + er;
        if (tx == 0 && rpos < 500) {
            int base = ((grp*4 + ch)*PROWS + rpos)*5;
            #pragma unroll
            for (int j = 0; j < 5; ++j) { pV[base+j] = lv[j]; pP[base+j] = lp[j]; }
        }
    }
}

// fused merge + edge MLP, 4 threads per src point (j-loop split in 32-chunks,
// pairwise shfl_xor sum — summation-order change only, within edge tolerance).
__global__ __launch_bounds__(256) void k_edge(const float* __restrict__ X,
        const float* __restrict__ W1, const float* __restrict__ b1,
        const float* __restrict__ W2, const float* __restrict__ b2,
        const float* __restrict__ pV, const int* __restrict__ pP,
        const int* __restrict__ sortedIdx, float* __restrict__ out) {
    __shared__ float w1t[128*36];
    __shared__ float b1l[128];
    __shared__ float w2l[128];
    const int tid = threadIdx.x;
    for (int idx = tid; idx < 33*128; idx += 256) {
        int f = idx >> 7, j = idx & 127;
        w1t[j*36 + f] = W1[idx];
    }
    if (tid < 128) { b1l[tid] = b1[tid]; w2l[tid] = W2[tid]; }
    __syncthreads();
    int rid4 = blockIdx.x*256 + tid;
    if (rid4 >= NGRP*BINSZ*4) return;
    const int rid = rid4 >> 2, quarter = rid4 & 3;
    const int grp = rid / BINSZ;
    const int rowLocal = rid - grp*BINSZ;
    const int b = grp / NBINS, g = grp - b*NBINS;
    // ---- merge 4 ch-partials (duplicated across the 4 quarters; deterministic) ----
    float lv[5]; int lp[5];
    {
        int pbase = (grp*4*PROWS + rowLocal)*5;
        #pragma unroll
        for (int j = 0; j < 5; ++j) { lv[j] = pV[pbase+j]; lp[j] = pP[pbase+j]; }
    }
    #pragma unroll
    for (int chh = 1; chh < 4; ++chh) {
        int pbase = ((grp*4 + chh)*PROWS + rowLocal)*5;
        #pragma unroll
        for (int j = 0; j < 5; ++j) {
            float v = pV[pbase+j]; int p = pP[pbase+j];
            INS_TIE(lv, lp, v, p);
        }
    }
    const int* sIdx = sortedIdx + b*NPTS + g*BINSZ;
    const int src = sIdx[rowLocal];
    int dd[5]; float vv[5];
    #pragma unroll
    for (int j = 0; j < 5; ++j) {
        dd[j] = sIdx[lp[j]];
        vv[j] = 1.f/(1.f + expf(-lv[j]));
    }
    #define CSWAP(i,j) { if (dd[i] > dd[j]) { int td=dd[i];dd[i]=dd[j];dd[j]=td; \
                         float tf=vv[i];vv[i]=vv[j];vv[j]=tf; } }
    CSWAP(0,1) CSWAP(3,4) CSWAP(2,4) CSWAP(2,3) CSWAP(1,4)
    CSWAP(0,3) CSWAP(0,2) CSWAP(1,3) CSWAP(1,2)
    #undef CSWAP
    const int base = b*EDGES_PER_BATCH + src*5;
    if (quarter == 0) {
        #pragma unroll
        for (int e = 0; e < 5; ++e) {
            out[EDGE_TOT   + base + e] = (float)src;
            out[2*EDGE_TOT + base + e] = (float)dd[e];
        }
    }
    // ---- edge MLP over j-range [quarter*32, quarter*32+32) ----
    float4 xs[4];
    {
        const float4* xp = (const float4*)(X + ((size_t)b*NPTS + src)*NFEAT);
        #pragma unroll
        for (int q = 0; q < 4; ++q) xs[q] = xp[q];
    }
    float4 xd[5][4];
    #pragma unroll
    for (int e = 0; e < 5; ++e) {
        const float4* xp = (const float4*)(X + ((size_t)b*NPTS + dd[e])*NFEAT);
        #pragma unroll
        for (int q = 0; q < 4; ++q) xd[e][q] = xp[q];
    }
    float acc[5] = {0.f,0.f,0.f,0.f,0.f};
    const int jEnd = quarter*32 + 32;
    for (int j = quarter*32; j < jEnd; ++j) {
        const float* wr = &w1t[j*36];
        float4 ws0 = ((const float4*)wr)[0];
        float4 ws1 = ((const float4*)wr)[1];
        float4 ws2 = ((const float4*)wr)[2];
        float4 ws3 = ((const float4*)wr)[3];
        float4 u0  = ((const float4*)(wr+16))[0];
        float4 u1  = ((const float4*)(wr+16))[1];
        float4 u2  = ((const float4*)(wr+16))[2];
        float4 u3  = ((const float4*)(wr+16))[3];
        float w32 = wr[32];
        float w2j = w2l[j];
        float sh = b1l[j]
            + xs[0].x*ws0.x + xs[0].y*ws0.y + xs[0].z*ws0.z + xs[0].w*ws0.w
            + xs[1].x*ws1.x + xs[1].y*ws1.y + xs[1].z*ws1.z + xs[1].w*ws1.w
            + xs[2].x*ws2.x + xs[2].y*ws2.y + xs[2].z*ws2.z + xs[2].w*ws2.w
            + xs[3].x*ws3.x + xs[3].y*ws3.y + xs[3].z*ws3.z + xs[3].w*ws3.w;
        #pragma unroll
        for (int e = 0; e < 5; ++e) {
            float h = sh
                + xd[e][0].x*u0.x + xd[e][0].y*u0.y + xd[e][0].z*u0.z + xd[e][0].w*u0.w
                + xd[e][1].x*u1.x + xd[e][1].y*u1.y + xd[e][1].z*u1.z + xd[e][1].w*u1.w
                + xd[e][2].x*u2.x + xd[e][2].y*u2.y + xd[e][2].z*u2.z + xd[e][2].w*u2.w
                + xd[e][3].x*u3.x + xd[e][3].y*u3.y + xd[e][3].z*u3.z + xd[e][3].w*u3.w;
            h += vv[e]*w32;
            h = (h > 0.f) ? h : expm1f(h);
            acc[e] += h * w2j;
        }
    }
    // pairwise reduce across the 4 quarters: ((q0+q1)+(q2+q3))
    #pragma unroll
    for (int e = 0; e < 5; ++e) {
        acc[e] += __shfl_xor(acc[e], 1, 64);
        acc[e] += __shfl_xor(acc[e], 2, 64);
    }
    if (quarter != 0) return;
    float b2v = b2[0];
    #pragma unroll
    for (int e = 0; e < 5; ++e) {
        out[base + e] = 1.f/(1.f + expf(-(acc[e] + b2v)));
    }
}

extern "C" void kernel_launch(void* const* d_in, const int* in_sizes, int n_in,
                              void* d_out, int out_size, void* d_ws, size_t ws_size,
                              hipStream_t stream) {
    const float* X   = (const float*)d_in[0];
    const float* We1 = (const float*)d_in[1];
    const float* be1 = (const float*)d_in[2];
    const float* We2 = (const float*)d_in[3];
    const float* be2 = (const float*)d_in[4];
    const float* Wd1 = (const float*)d_in[5];
    const float* bd1 = (const float*)d_in[6];
    const float* Wd2 = (const float*)d_in[7];
    const float* bd2 = (const float*)d_in[8];
    const float* R   = (const float*)d_in[9];
    float* out = (float*)d_out;

    // workspace layout (~54 MB)
    float* enc      = (float*)d_ws;                       // 80000*128 f32
    int*   binIdx   = (int*)(enc + (size_t)TOTPTS*128);   // 80000
    int*   sortedIdx= binIdx + TOTPTS;                    // 80000
    int*   hist     = sortedIdx + TOTPTS;                 // 160
    float* pV       = (float*)(hist + NBATCH*NBINS);      // 160*4*512*5 = 1638400
    int*   pP       = (int*)(pV + (size_t)NGRP*4*PROWS*5);// 1638400

    k_enc  <<<TOTPTS/32, 256, 0, stream>>>(X, We1, be1, We2, be2, enc, hist);
    k_bins <<<(TOTPTS+255)/256, 256, 0, stream>>>(enc, R, binIdx, hist);
    k_sort <<<NBATCH*NBINS, 256, 0, stream>>>(binIdx, hist, sortedIdx);
    k_gram <<<NGRP*16, 256, 0, stream>>>(enc, sortedIdx, pV, pP);
    k_edge <<<(NGRP*BINSZ*4+255)/256, 256, 0, stream>>>(X, Wd1, bd1, Wd2, bd2,
                                                        pV, pP, sortedIdx, out);
}

// Round 11
// 491.627 us; speedup vs baseline: 1.5499x; 1.1695x over previous
//
#include <hip/hip_runtime.h>
#include <cmath>

#define NPTS 10000
#define NBATCH 8
#define NFEAT 16
#define DDIM 128
#define NBINS 20
#define BINSZ 500
#define KSEL 5
#define EDGES_PER_BATCH (NPTS*KSEL)        // 50000
#define EDGE_TOT (NBATCH*EDGES_PER_BATCH)  // 400000
#define TOTPTS (NBATCH*NPTS)               // 80000
#define NGRP (NBATCH*NBINS)                // 160
#define PROWS 512                          // padded rows per (grp,ch) partial slab

// enc = ELU(X@W1+b1)@W2+b2 ; 32 points per block, 256 threads.
// Block 0 also zeroes the bin histogram (k_bins runs after k_enc completes).
__global__ __launch_bounds__(256) void k_enc(const float* __restrict__ X,
        const float* __restrict__ W1, const float* __restrict__ b1,
        const float* __restrict__ W2, const float* __restrict__ b2,
        float* __restrict__ enc, int* __restrict__ hist) {
    __shared__ float hT[128*36];
    const int tid = threadIdx.x;
    const int P0 = blockIdx.x * 32;
    if (blockIdx.x == 0 && tid < NBATCH*NBINS) hist[tid] = 0;
    #pragma unroll
    for (int i = 0; i < 16; ++i) {
        int idx = i*256 + tid;
        int p = idx >> 7;
        int j = idx & 127;
        const float* xr = X + (size_t)(P0 + p)*NFEAT;
        float h = b1[j];
        #pragma unroll
        for (int f = 0; f < 16; ++f) h += xr[f] * W1[f*128 + j];
        h = (h > 0.f) ? h : expm1f(h);
        hT[j*36 + p] = h;
    }
    __syncthreads();
    const int jt = tid & 31, pt = tid >> 5;
    const int j0 = jt*4, p0 = pt*4;
    float acc[4][4];
    #pragma unroll
    for (int ep = 0; ep < 4; ++ep)
        #pragma unroll
        for (int ej = 0; ej < 4; ++ej) acc[ep][ej] = b2[j0+ej];
    for (int k = 0; k < 128; ++k) {
        float4 hv = *(const float4*)&hT[k*36 + p0];
        float4 wv = *(const float4*)&W2[k*128 + j0];
        float hvv[4] = {hv.x,hv.y,hv.z,hv.w};
        float wvv[4] = {wv.x,wv.y,wv.z,wv.w};
        #pragma unroll
        for (int ep = 0; ep < 4; ++ep)
            #pragma unroll
            for (int ej = 0; ej < 4; ++ej) acc[ep][ej] += hvv[ep]*wvv[ej];
    }
    #pragma unroll
    for (int ep = 0; ep < 4; ++ep) {
        float4 o = {acc[ep][0],acc[ep][1],acc[ep][2],acc[ep][3]};
        *(float4*)&enc[(size_t)(P0+p0+ep)*128 + j0] = o;
    }
}

// mul = enc @ R[:, :10]; bin = argmax([mul, -mul]) first-max-wins; histogram
__global__ __launch_bounds__(256) void k_bins(const float* __restrict__ enc,
        const float* __restrict__ R, int* __restrict__ binIdx, int* __restrict__ hist) {
    __shared__ float Rl[128*10];
    const int tid = threadIdx.x;
    for (int idx = tid; idx < 1280; idx += 256) {
        int d = idx / 10, i = idx % 10;
        Rl[idx] = R[d*100 + i];
    }
    __syncthreads();
    int gp = blockIdx.x*256 + tid;
    if (gp >= TOTPTS) return;
    float acc[10];
    #pragma unroll
    for (int i = 0; i < 10; ++i) acc[i] = 0.f;
    const float4* er = (const float4*)(enc + (size_t)gp*128);
    for (int d4 = 0; d4 < 32; ++d4) {
        float4 e4 = er[d4];
        float ev[4] = {e4.x,e4.y,e4.z,e4.w};
        #pragma unroll
        for (int q = 0; q < 4; ++q) {
            const float* rr = &Rl[(d4*4+q)*10];
            #pragma unroll
            for (int i = 0; i < 10; ++i) acc[i] += ev[q]*rr[i];
        }
    }
    float best = acc[0]; int bi = 0;
    #pragma unroll
    for (int i = 1; i < 10; ++i) if (acc[i] > best) { best = acc[i]; bi = i; }
    #pragma unroll
    for (int i = 0; i < 10; ++i) { float v = -acc[i]; if (v > best) { best = v; bi = 10+i; } }
    binIdx[gp] = bi;
    atomicAdd(&hist[(gp/NPTS)*NBINS + bi], 1);
}

// stable counting-sort scatter: one block per (batch,bin)
__global__ __launch_bounds__(256) void k_sort(const int* __restrict__ binIdx,
        const int* __restrict__ hist, int* __restrict__ sortedIdx) {
    const int b = blockIdx.x / NBINS;
    const int bin = blockIdx.x % NBINS;
    const int tid = threadIdx.x;
    __shared__ int wtot[4];
    int off = 0;
    for (int k = 0; k < bin; ++k) off += hist[b*NBINS + k];
    const int* bptr = binIdx + b*NPTS;
    int* sptr = sortedIdx + b*NPTS;
    const int lane = tid & 63, wid = tid >> 6;
    for (int c = 0; c < 40; ++c) {
        int i = c*256 + tid;
        bool pred = (i < NPTS) && (bptr[i] == bin);
        unsigned long long mask = __ballot(pred);
        int rank = __popcll(mask & ((1ULL << lane) - 1ULL));
        if (lane == 0) wtot[wid] = __popcll(mask);
        __syncthreads();
        int prefix = 0;
        #pragma unroll
        for (int w = 0; w < 4; ++w) prefix += (w < wid) ? wtot[w] : 0;
        int total = wtot[0]+wtot[1]+wtot[2]+wtot[3];
        if (pred) sptr[off + prefix + rank] = i;
        off += total;
        __syncthreads();
    }
}

// insert (v,p) into sorted-desc 5-list, strict > (candidates arrive ascending p)
#define INS_STRICT(VV,PP,v,p) do { \
  if ((v) > VV[4]) { \
    if ((v) > VV[3]) { VV[4]=VV[3]; PP[4]=PP[3]; \
      if ((v) > VV[2]) { VV[3]=VV[2]; PP[3]=PP[2]; \
        if ((v) > VV[1]) { VV[2]=VV[1]; PP[2]=PP[1]; \
          if ((v) > VV[0]) { VV[1]=VV[0]; PP[1]=PP[0]; VV[0]=(v); PP[0]=(p); } \
          else { VV[1]=(v); PP[1]=(p); } } \
        else { VV[2]=(v); PP[2]=(p); } } \
      else { VV[3]=(v); PP[3]=(p); } } \
    else { VV[4]=(v); PP[4]=(p); } } } while(0)

// tie-aware better-than: (v desc, p asc) — exact lax.top_k semantics
#define BT(va,pa,vb,pb) (((va) > (vb)) || (((va) == (vb)) && ((pa) < (pb))))
#define INS_TIE(VV,PP,v,p) do { \
  if (BT(v,p,VV[4],PP[4])) { \
    if (BT(v,p,VV[3],PP[3])) { VV[4]=VV[3]; PP[4]=PP[3]; \
      if (BT(v,p,VV[2],PP[2])) { VV[3]=VV[2]; PP[3]=PP[2]; \
        if (BT(v,p,VV[1],PP[1])) { VV[2]=VV[1]; PP[2]=PP[1]; \
          if (BT(v,p,VV[0],PP[0])) { VV[1]=VV[0]; PP[1]=PP[0]; VV[0]=(v); PP[0]=(p); } \
          else { VV[1]=(v); PP[1]=(p); } } \
        else { VV[2]=(v); PP[2]=(p); } } \
      else { VV[3]=(v); PP[3]=(p); } } \
    else { VV[4]=(v); PP[4]=(p); } } } while(0)

// Gram partial — r6-verified optimum of this family (203 µs): 256 threads,
// 128x128 block tile, 4 rows x 16 cols per thread, conflict-free swizzles,
// fold fully unrolled (runtime acc[][] indexing spills to scratch — r9 bug).
// blockIdx = unit*160 + grp (XCD-aligned, r3-verified).
// Tile-shape A/B results: 4x16=203µs (r6) < 8x8=297µs (r10) < 8x16=spill (r8).
__global__ __launch_bounds__(256, 4) void k_gram(const float* __restrict__ enc,
        const int* __restrict__ sortedIdx, float* __restrict__ pV, int* __restrict__ pP) {
    __shared__ __align__(16) float As[32][128];   // [k][row]     16 KB
    __shared__ __align__(16) float Bs[32][128];   // [k][col swz] 16 KB
    __shared__ int gIdx[500];
    const int tid = threadIdx.x;
    const int unit = blockIdx.x / 160;      // rowTile*4 + ch
    const int grp  = blockIdx.x - unit*160;
    const int rowTile = unit >> 2, ch = unit & 3;
    const int b = grp / NBINS, g = grp - b*NBINS;
    const int tx = tid & 7;                 // col group: cols tx*16..tx*16+15
    const int ty = tid >> 3;                // row group 0..31: rows ty*4..ty*4+3
    for (int i = tid; i < 500; i += 256) gIdx[i] = sortedIdx[b*NPTS + g*500 + i];
    __syncthreads();

    const int rowBase = rowTile * 128;
    const int rotq = (tx >> 1) & 3;         // B bank-swizzle rotation (in quads)
    const int sRow = tid >> 1;              // A staging: row 0..127 (2 thr/row)
    const int sKh  = (tid & 1) * 16;        // A staging: k-half
    const size_t encBase = (size_t)b * NPTS * 128;
    const float* encA = enc + encBase + (size_t)gIdx[min(rowBase + sRow, 499)] * 128;
    const int bCol = tid >> 1;              // B staging: col 0..127 (2 thr/col)
    const float* encB = enc + encBase + (size_t)gIdx[min(ch*128 + bCol, 499)] * 128;
    // B col slot swizzle: slot(c) = (c&~15) | ((c%16 + 4*((c>>5)&3)) & 15)
    const int c_sw = (bCol & ~15) | (((bCol & 15) + 4*((bCol >> 5) & 3)) & 15);

    float acc[4][16];
    #pragma unroll
    for (int er = 0; er < 4; ++er)
        #pragma unroll
        for (int ec = 0; ec < 16; ++ec) acc[er][ec] = 0.f;

    #pragma unroll 1
    for (int kc = 0; kc < 128; kc += 32) {
        __syncthreads();   // previous chunk's LDS reads done
        { // stage A: 128 rows x 32 k (transpose to [k][row]); 16 floats/thread
            const float* eA = encA + kc + sKh;
            float4 v0 = *(const float4*)(eA + 0);
            float4 v1 = *(const float4*)(eA + 4);
            float4 v2 = *(const float4*)(eA + 8);
            float4 v3 = *(const float4*)(eA + 12);
            As[sKh+ 0][sRow]=v0.x; As[sKh+ 1][sRow]=v0.y; As[sKh+ 2][sRow]=v0.z; As[sKh+ 3][sRow]=v0.w;
            As[sKh+ 4][sRow]=v1.x; As[sKh+ 5][sRow]=v1.y; As[sKh+ 6][sRow]=v1.z; As[sKh+ 7][sRow]=v1.w;
            As[sKh+ 8][sRow]=v2.x; As[sKh+ 9][sRow]=v2.y; As[sKh+10][sRow]=v2.z; As[sKh+11][sRow]=v2.w;
            As[sKh+12][sRow]=v3.x; As[sKh+13][sRow]=v3.y; As[sKh+14][sRow]=v3.z; As[sKh+15][sRow]=v3.w;
        }
        { // stage B: 128 cols x 32 k (transpose, swizzled col slot); 16 floats/thread
            const float* eB = encB + kc + sKh;
            float4 v0 = *(const float4*)(eB + 0);
            float4 v1 = *(const float4*)(eB + 4);
            float4 v2 = *(const float4*)(eB + 8);
            float4 v3 = *(const float4*)(eB + 12);
            Bs[sKh+ 0][c_sw]=v0.x; Bs[sKh+ 1][c_sw]=v0.y; Bs[sKh+ 2][c_sw]=v0.z; Bs[sKh+ 3][c_sw]=v0.w;
            Bs[sKh+ 4][c_sw]=v1.x; Bs[sKh+ 5][c_sw]=v1.y; Bs[sKh+ 6][c_sw]=v1.z; Bs[sKh+ 7][c_sw]=v1.w;
            Bs[sKh+ 8][c_sw]=v2.x; Bs[sKh+ 9][c_sw]=v2.y; Bs[sKh+10][c_sw]=v2.z; Bs[sKh+11][c_sw]=v2.w;
            Bs[sKh+12][c_sw]=v3.x; Bs[sKh+13][c_sw]=v3.y; Bs[sKh+14][c_sw]=v3.z; Bs[sKh+15][c_sw]=v3.w;
        }
        __syncthreads();
        #pragma unroll 4
        for (int k = 0; k < 32; ++k) {
            float4 a4 = *(const float4*)&As[k][ty*4];
            float av[4] = {a4.x, a4.y, a4.z, a4.w};
            #pragma unroll
            for (int j = 0; j < 4; ++j) {
                int q = (j + rotq) & 3;                      // de-swizzle
                float4 b4 = *(const float4*)&Bs[k][tx*16 + q*4];
                float bv[4] = {b4.x, b4.y, b4.z, b4.w};
                #pragma unroll
                for (int er = 0; er < 4; ++er)
                    #pragma unroll
                    for (int m = 0; m < 4; ++m)
                        acc[er][m + j*4] += av[er] * bv[m];
            }
        }
    }

    // per-thread top-5 of my 16 cols (absolute cpos, ascending -> strict >)
    float tkv[4][5]; int tkp[4][5];
    #pragma unroll
    for (int er = 0; er < 4; ++er) {
        #pragma unroll
        for (int j = 0; j < 5; ++j) { tkv[er][j] = -3.4e38f; tkp[er][j] = 0x7fffffff; }
        #pragma unroll
        for (int ec = 0; ec < 16; ++ec) {
            int cpos = ch*128 + tx*16 + ec;
            if (cpos < 500) INS_STRICT(tkv[er], tkp[er], acc[er][ec], cpos);
        }
    }
    // merge across the 8 tx lanes (3 xor steps), tie-aware
    #pragma unroll
    for (int m = 1; m < 8; m <<= 1) {
        #pragma unroll
        for (int er = 0; er < 4; ++er) {
            float pv[5]; int pp[5];
            #pragma unroll
            for (int j = 0; j < 5; ++j) {
                pv[j] = __shfl_xor(tkv[er][j], m, 64);
                pp[j] = __shfl_xor(tkp[er][j], m, 64);
            }
            #pragma unroll
            for (int j = 0; j < 5; ++j) INS_TIE(tkv[er], tkp[er], pv[j], pp[j]);
        }
    }
    if (tx != 0) return;
    #pragma unroll
    for (int er = 0; er < 4; ++er) {
        int rpos = rowBase + ty*4 + er;
        if (rpos < 500) {
            int base = ((grp*4 + ch)*PROWS + rpos)*5;
            #pragma unroll
            for (int j = 0; j < 5; ++j) { pV[base+j] = tkv[er][j]; pP[base+j] = tkp[er][j]; }
        }
    }
}

// fused merge + edge MLP, 4 threads per src point (j-loop split in 32-chunks,
// pairwise shfl_xor sum — summation-order change only, within edge tolerance).
__global__ __launch_bounds__(256) void k_edge(const float* __restrict__ X,
        const float* __restrict__ W1, const float* __restrict__ b1,
        const float* __restrict__ W2, const float* __restrict__ b2,
        const float* __restrict__ pV, const int* __restrict__ pP,
        const int* __restrict__ sortedIdx, float* __restrict__ out) {
    __shared__ float w1t[128*36];
    __shared__ float b1l[128];
    __shared__ float w2l[128];
    const int tid = threadIdx.x;
    for (int idx = tid; idx < 33*128; idx += 256) {
        int f = idx >> 7, j = idx & 127;
        w1t[j*36 + f] = W1[idx];
    }
    if (tid < 128) { b1l[tid] = b1[tid]; w2l[tid] = W2[tid]; }
    __syncthreads();
    int rid4 = blockIdx.x*256 + tid;
    if (rid4 >= NGRP*BINSZ*4) return;
    const int rid = rid4 >> 2, quarter = rid4 & 3;
    const int grp = rid / BINSZ;
    const int rowLocal = rid - grp*BINSZ;
    const int b = grp / NBINS, g = grp - b*NBINS;
    // ---- merge 4 ch-partials (duplicated across the 4 quarters; deterministic) ----
    float lv[5]; int lp[5];
    {
        int pbase = (grp*4*PROWS + rowLocal)*5;
        #pragma unroll
        for (int j = 0; j < 5; ++j) { lv[j] = pV[pbase+j]; lp[j] = pP[pbase+j]; }
    }
    #pragma unroll
    for (int chh = 1; chh < 4; ++chh) {
        int pbase = ((grp*4 + chh)*PROWS + rowLocal)*5;
        #pragma unroll
        for (int j = 0; j < 5; ++j) {
            float v = pV[pbase+j]; int p = pP[pbase+j];
            INS_TIE(lv, lp, v, p);
        }
    }
    const int* sIdx = sortedIdx + b*NPTS + g*BINSZ;
    const int src = sIdx[rowLocal];
    int dd[5]; float vv[5];
    #pragma unroll
    for (int j = 0; j < 5; ++j) {
        dd[j] = sIdx[lp[j]];
        vv[j] = 1.f/(1.f + expf(-lv[j]));
    }
    #define CSWAP(i,j) { if (dd[i] > dd[j]) { int td=dd[i];dd[i]=dd[j];dd[j]=td; \
                         float tf=vv[i];vv[i]=vv[j];vv[j]=tf; } }
    CSWAP(0,1) CSWAP(3,4) CSWAP(2,4) CSWAP(2,3) CSWAP(1,4)
    CSWAP(0,3) CSWAP(0,2) CSWAP(1,3) CSWAP(1,2)
    #undef CSWAP
    const int base = b*EDGES_PER_BATCH + src*5;
    if (quarter == 0) {
        #pragma unroll
        for (int e = 0; e < 5; ++e) {
            out[EDGE_TOT   + base + e] = (float)src;
            out[2*EDGE_TOT + base + e] = (float)dd[e];
        }
    }
    // ---- edge MLP over j-range [quarter*32, quarter*32+32) ----
    float4 xs[4];
    {
        const float4* xp = (const float4*)(X + ((size_t)b*NPTS + src)*NFEAT);
        #pragma unroll
        for (int q = 0; q < 4; ++q) xs[q] = xp[q];
    }
    float4 xd[5][4];
    #pragma unroll
    for (int e = 0; e < 5; ++e) {
        const float4* xp = (const float4*)(X + ((size_t)b*NPTS + dd[e])*NFEAT);
        #pragma unroll
        for (int q = 0; q < 4; ++q) xd[e][q] = xp[q];
    }
    float acc[5] = {0.f,0.f,0.f,0.f,0.f};
    const int jEnd = quarter*32 + 32;
    for (int j = quarter*32; j < jEnd; ++j) {
        const float* wr = &w1t[j*36];
        float4 ws0 = ((const float4*)wr)[0];
        float4 ws1 = ((const float4*)wr)[1];
        float4 ws2 = ((const float4*)wr)[2];
        float4 ws3 = ((const float4*)wr)[3];
        float4 u0  = ((const float4*)(wr+16))[0];
        float4 u1  = ((const float4*)(wr+16))[1];
        float4 u2  = ((const float4*)(wr+16))[2];
        float4 u3  = ((const float4*)(wr+16))[3];
        float w32 = wr[32];
        float w2j = w2l[j];
        float sh = b1l[j]
            + xs[0].x*ws0.x + xs[0].y*ws0.y + xs[0].z*ws0.z + xs[0].w*ws0.w
            + xs[1].x*ws1.x + xs[1].y*ws1.y + xs[1].z*ws1.z + xs[1].w*ws1.w
            + xs[2].x*ws2.x + xs[2].y*ws2.y + xs[2].z*ws2.z + xs[2].w*ws2.w
            + xs[3].x*ws3.x + xs[3].y*ws3.y + xs[3].z*ws3.z + xs[3].w*ws3.w;
        #pragma unroll
        for (int e = 0; e < 5; ++e) {
            float h = sh
                + xd[e][0].x*u0.x + xd[e][0].y*u0.y + xd[e][0].z*u0.z + xd[e][0].w*u0.w
                + xd[e][1].x*u1.x + xd[e][1].y*u1.y + xd[e][1].z*u1.z + xd[e][1].w*u1.w
                + xd[e][2].x*u2.x + xd[e][2].y*u2.y + xd[e][2].z*u2.z + xd[e][2].w*u2.w
                + xd[e][3].x*u3.x + xd[e][3].y*u3.y + xd[e][3].z*u3.z + xd[e][3].w*u3.w;
            h += vv[e]*w32;
            h = (h > 0.f) ? h : expm1f(h);
            acc[e] += h * w2j;
        }
    }
    // pairwise reduce across the 4 quarters: ((q0+q1)+(q2+q3))
    #pragma unroll
    for (int e = 0; e < 5; ++e) {
        acc[e] += __shfl_xor(acc[e], 1, 64);
        acc[e] += __shfl_xor(acc[e], 2, 64);
    }
    if (quarter != 0) return;
    float b2v = b2[0];
    #pragma unroll
    for (int e = 0; e < 5; ++e) {
        out[base + e] = 1.f/(1.f + expf(-(acc[e] + b2v)));
    }
}

extern "C" void kernel_launch(void* const* d_in, const int* in_sizes, int n_in,
                              void* d_out, int out_size, void* d_ws, size_t ws_size,
                              hipStream_t stream) {
    const float* X   = (const float*)d_in[0];
    const float* We1 = (const float*)d_in[1];
    const float* be1 = (const float*)d_in[2];
    const float* We2 = (const float*)d_in[3];
    const float* be2 = (const float*)d_in[4];
    const float* Wd1 = (const float*)d_in[5];
    const float* bd1 = (const float*)d_in[6];
    const float* Wd2 = (const float*)d_in[7];
    const float* bd2 = (const float*)d_in[8];
    const float* R   = (const float*)d_in[9];
    float* out = (float*)d_out;

    // workspace layout (~54 MB)
    float* enc      = (float*)d_ws;                       // 80000*128 f32
    int*   binIdx   = (int*)(enc + (size_t)TOTPTS*128);   // 80000
    int*   sortedIdx= binIdx + TOTPTS;                    // 80000
    int*   hist     = sortedIdx + TOTPTS;                 // 160
    float* pV       = (float*)(hist + NBATCH*NBINS);      // 160*4*512*5 = 1638400
    int*   pP       = (int*)(pV + (size_t)NGRP*4*PROWS*5);// 1638400

    k_enc  <<<TOTPTS/32, 256, 0, stream>>>(X, We1, be1, We2, be2, enc, hist);
    k_bins <<<(TOTPTS+255)/256, 256, 0, stream>>>(enc, R, binIdx, hist);
    k_sort <<<NBATCH*NBINS, 256, 0, stream>>>(binIdx, hist, sortedIdx);
    k_gram <<<NGRP*16, 256, 0, stream>>>(enc, sortedIdx, pV, pP);
    k_edge <<<(NGRP*BINSZ*4+255)/256, 256, 0, stream>>>(X, Wd1, bd1, Wd2, bd2,
                                                        pV, pP, sortedIdx, out);
}